// Round 18
// baseline (168.937 us; speedup 1.0000x reference)
//
#include <hip/hip_runtime.h>

typedef unsigned short u16;
typedef unsigned int u32;
typedef __bf16 bf16x8 __attribute__((ext_vector_type(8)));
typedef float f32x4 __attribute__((ext_vector_type(4)));

#define GRID_G 96
#define DMODEL 512
#define NTOK (GRID_G * GRID_G)

__device__ __forceinline__ u16 f2bf(float f) {
  return __builtin_bit_cast(u16, (__bf16)f);   // single v_cvt (RNE)
}
__device__ __forceinline__ float bf2f(u16 h) {
  return __builtin_bit_cast(float, ((u32)h) << 16);
}
__device__ __forceinline__ void unpack8(uint4 u, float* f) {
  f[0] = __builtin_bit_cast(float, u.x << 16);
  f[1] = __builtin_bit_cast(float, u.x & 0xffff0000u);
  f[2] = __builtin_bit_cast(float, u.y << 16);
  f[3] = __builtin_bit_cast(float, u.y & 0xffff0000u);
  f[4] = __builtin_bit_cast(float, u.z << 16);
  f[5] = __builtin_bit_cast(float, u.z & 0xffff0000u);
  f[6] = __builtin_bit_cast(float, u.w << 16);
  f[7] = __builtin_bit_cast(float, u.w & 0xffff0000u);
}
// gelu (tanh form, stable): max dev vs erf-gelu ~3e-4 — far under threshold
__device__ __forceinline__ float gelu_fast(float x) {
  float y = 0.7978845608f * (x + 0.044715f * x * x * x);
  float a = fabsf(y);
  float e = __expf(-2.0f * a);
  float th = (1.0f - e) / (1.0f + e);
  th = __builtin_copysignf(th, y);
  return 0.5f * x * (1.0f + th);
}

// ============ merged prep: weight transposes + bias concat + LN1 (1 launch) ============
__device__ __forceinline__ void tr_tile(const float* __restrict__ src,
                                        u16* __restrict__ dst, int R, int C,
                                        int bx, int by, float (*tile)[33]) {
  int tx = threadIdx.x & 31, ty = threadIdx.x >> 5;
#pragma unroll
  for (int i = 0; i < 4; ++i) {
    int r = ty + i * 8;
    tile[r][tx] = src[(size_t)(by * 32 + r) * C + (bx * 32 + tx)];
  }
  __syncthreads();
#pragma unroll
  for (int i = 0; i < 4; ++i) {
    int c = ty + i * 8;
    dst[(size_t)(bx * 32 + c) * R + (by * 32 + tx)] = f2bf(tile[tx][c]);
  }
}

__global__ __launch_bounds__(256) void k_prep(
    const float* __restrict__ Wq, const float* __restrict__ Wk,
    const float* __restrict__ Wv, const float* __restrict__ Wo,
    const float* __restrict__ W1, const float* __restrict__ W2,
    const float* __restrict__ bq, const float* __restrict__ bk,
    const float* __restrict__ bv, const float* __restrict__ x,
    const float* __restrict__ g1, const float* __restrict__ b1,
    u16* __restrict__ WQT, u16* __restrict__ WKT, u16* __restrict__ WVT,
    u16* __restrict__ WOT, u16* __restrict__ W1T, u16* __restrict__ W2T,
    float* __restrict__ BCAT, u16* __restrict__ H) {
  __shared__ float tile[32][33];
  const int b = blockIdx.x;
  if (b < 1024) {            // 4x 512x512 transpose
    int z = b >> 8, sub = b & 255;
    const float* s = z == 0 ? Wq : z == 1 ? Wk : z == 2 ? Wv : Wo;
    u16* d = z == 0 ? WQT : z == 1 ? WKT : z == 2 ? WVT : WOT;
    tr_tile(s, d, 512, 512, sub & 15, sub >> 4, tile);
  } else if (b < 2048) {     // W1 [512][2048] -> W1T [2048][512]
    int idx = b - 1024;
    tr_tile(W1, W1T, 512, 2048, idx & 63, idx >> 6, tile);
  } else if (b < 3072) {     // W2 [2048][512] -> W2T [512][2048]
    int idx = b - 2048;
    tr_tile(W2, W2T, 2048, 512, idx & 15, idx >> 4, tile);
  } else if (b < 3078) {     // bias concat
    int i = (b - 3072) * 256 + threadIdx.x;
    if (i < 512) BCAT[i] = bq[i];
    else if (i < 1024) BCAT[i] = bk[i - 512];
    else if (i < 1536) BCAT[i] = bv[i - 1024];
  } else {                   // LN1: x -> H (bf16), one wave/row
    int tid = threadIdx.x, wid = tid >> 6, lane = tid & 63;
    int row = (b - 3078) * 4 + wid;
    const float* xr = x + (size_t)row * DMODEL;
    float4 v0 = *(const float4*)(xr + lane * 4);
    float4 v1 = *(const float4*)(xr + 256 + lane * 4);
    float s = v0.x + v0.y + v0.z + v0.w + v1.x + v1.y + v1.z + v1.w;
    float sq = v0.x * v0.x + v0.y * v0.y + v0.z * v0.z + v0.w * v0.w +
               v1.x * v1.x + v1.y * v1.y + v1.z * v1.z + v1.w * v1.w;
#pragma unroll
    for (int m = 1; m < 64; m <<= 1) {
      s += __shfl_xor(s, m);
      sq += __shfl_xor(sq, m);
    }
    float mean = s * (1.0f / DMODEL);
    float rstd = rsqrtf(sq * (1.0f / DMODEL) - mean * mean + 1e-5f);
    float4 ga = *(const float4*)(g1 + lane * 4);
    float4 gb = *(const float4*)(g1 + 256 + lane * 4);
    float4 ba = *(const float4*)(b1 + lane * 4);
    float4 bb = *(const float4*)(b1 + 256 + lane * 4);
    ushort4 o0, o1;
    o0.x = f2bf((v0.x - mean) * rstd * ga.x + ba.x);
    o0.y = f2bf((v0.y - mean) * rstd * ga.y + ba.y);
    o0.z = f2bf((v0.z - mean) * rstd * ga.z + ba.z);
    o0.w = f2bf((v0.w - mean) * rstd * ga.w + ba.w);
    o1.x = f2bf((v1.x - mean) * rstd * gb.x + bb.x);
    o1.y = f2bf((v1.y - mean) * rstd * gb.y + bb.y);
    o1.z = f2bf((v1.z - mean) * rstd * gb.z + bb.z);
    o1.w = f2bf((v1.w - mean) * rstd * gb.w + bb.w);
    u16* op = H + (size_t)row * DMODEL;
    *(ushort4*)(op + lane * 4) = o0;
    *(ushort4*)(op + 256 + lane * 4) = o1;
  }
}

// -------- LN2: bf16 y -> bf16 h2, one wave per row --------
__global__ __launch_bounds__(256) void k_layernorm_b2b(
    const u16* __restrict__ yb, const float* __restrict__ g,
    const float* __restrict__ b, u16* __restrict__ out) {
  int tid = threadIdx.x, wid = tid >> 6, lane = tid & 63;
  int row = blockIdx.x * 4 + wid;
  float v[8];
  unpack8(*(const uint4*)(yb + (size_t)row * DMODEL + lane * 8), v);
  float s = 0.f, sq = 0.f;
#pragma unroll
  for (int e = 0; e < 8; ++e) { s += v[e]; sq += v[e] * v[e]; }
#pragma unroll
  for (int m = 1; m < 64; m <<= 1) {
    s += __shfl_xor(s, m);
    sq += __shfl_xor(sq, m);
  }
  float mean = s * (1.0f / DMODEL);
  float rstd = rsqrtf(sq * (1.0f / DMODEL) - mean * mean + 1e-5f);
  float4 ga = *(const float4*)(g + lane * 8);
  float4 gb = *(const float4*)(g + lane * 8 + 4);
  float4 ba = *(const float4*)(b + lane * 8);
  float4 bb = *(const float4*)(b + lane * 8 + 4);
  float gg[8] = {ga.x, ga.y, ga.z, ga.w, gb.x, gb.y, gb.z, gb.w};
  float bbv[8] = {ba.x, ba.y, ba.z, ba.w, bb.x, bb.y, bb.z, bb.w};
  uint4 o;
  u32 r[8];
#pragma unroll
  for (int e = 0; e < 8; ++e) r[e] = f2bf((v[e] - mean) * rstd * gg[e] + bbv[e]);
  o.x = r[0] | (r[1] << 16);
  o.y = r[2] | (r[3] << 16);
  o.z = r[4] | (r[5] << 16);
  o.w = r[6] | (r[7] << 16);
  *(uint4*)(out + (size_t)row * DMODEL + lane * 8) = o;
}

// ---------- local attention: one wave/token, 4x16-lane group reduction ----------
__global__ __launch_bounds__(256) void k_attn(
    const u16* __restrict__ q, const u16* __restrict__ kk,
    const u16* __restrict__ vv, const int* __restrict__ gpos,
    u16* __restrict__ out) {
  int tid = threadIdx.x, wid = tid >> 6, lane = tid & 63;
  const int nwg = gridDim.x, bid = blockIdx.x;
  const int l = ((bid & 7) * (nwg >> 3)) + (bid >> 3);   // nwg % 8 == 0
  int n = l * 4 + wid;
  int px = gpos[2 * n], py = gpos[2 * n + 1];
  const int g = lane >> 4, li = lane & 15;

  float qf[4][8];
#pragma unroll
  for (int i = 0; i < 4; ++i)
    unpack8(*(const uint4*)(q + (size_t)n * DMODEL + (li + 16 * i) * 8), qf[i]);

  float myw[6];
  bool myok[6];
#pragma unroll
  for (int jr = 0; jr < 6; ++jr) {
    int j = jr * 4 + g;
    int jj = j < 12 ? j : j + 1;           // skip (0,0)
    int dx = jj / 5 - 2, dy = jj % 5 - 2;
    int nx = px + dx, ny = py + dy;
    bool ok = (nx >= 0) && (nx < GRID_G) && (ny >= 0) && (ny < GRID_G);
    int id = ok ? nx * GRID_G + ny : 0;
    myok[jr] = ok;
    const u16* kr = kk + (size_t)id * DMODEL;
    float p = 0.f;
#pragma unroll
    for (int i = 0; i < 4; ++i) {
      float kf[8];
      unpack8(*(const uint4*)(kr + (li + 16 * i) * 8), kf);
#pragma unroll
      for (int e = 0; e < 8; ++e) p += qf[i][e] * kf[e];
    }
    p += __shfl_xor(p, 1);
    p += __shfl_xor(p, 2);
    p += __shfl_xor(p, 4);
    p += __shfl_xor(p, 8);
    myw[jr] = p * 0.04419417382415922f;    // 1/sqrt(512)
  }
  float mx = -3.0e38f;
#pragma unroll
  for (int jr = 0; jr < 6; ++jr)
    if (myok[jr]) mx = fmaxf(mx, myw[jr]);
  mx = fmaxf(mx, __shfl_xor(mx, 16));
  mx = fmaxf(mx, __shfl_xor(mx, 32));
  float ws = 0.f;
#pragma unroll
  for (int jr = 0; jr < 6; ++jr) {
    myw[jr] = myok[jr] ? __expf(myw[jr] - mx) : 0.f;
    ws += myw[jr];
  }
  ws += __shfl_xor(ws, 16);
  ws += __shfl_xor(ws, 32);
  float inv = __builtin_amdgcn_rcpf(ws);   // err ~1e-6, negligible

  float acc[8] = {0, 0, 0, 0, 0, 0, 0, 0};
#pragma unroll
  for (int j = 0; j < 24; ++j) {
    float wj = __shfl(myw[j >> 2], (j & 3) * 16);   // group (j&3) holds it
    int jj = j < 12 ? j : j + 1;
    int dx = jj / 5 - 2, dy = jj % 5 - 2;
    int nx = px + dx, ny = py + dy;
    bool ok = (nx >= 0) && (nx < GRID_G) && (ny >= 0) && (ny < GRID_G);
    int id = ok ? nx * GRID_G + ny : 0;    // wj==0 for invalid -> harmless
    float vf[8];
    unpack8(*(const uint4*)(vv + (size_t)id * DMODEL + lane * 8), vf);
#pragma unroll
    for (int e = 0; e < 8; ++e) acc[e] += wj * vf[e];
  }
  uint4 o;
  o.x = (u32)f2bf(acc[0] * inv) | ((u32)f2bf(acc[1] * inv) << 16);
  o.y = (u32)f2bf(acc[2] * inv) | ((u32)f2bf(acc[3] * inv) << 16);
  o.z = (u32)f2bf(acc[4] * inv) | ((u32)f2bf(acc[5] * inv) << 16);
  o.w = (u32)f2bf(acc[6] * inv) | ((u32)f2bf(acc[7] * inv) << 16);
  *(uint4*)(out + (size_t)n * DMODEL + lane * 8) = o;
}

#define BARR { __builtin_amdgcn_s_barrier(); __builtin_amdgcn_sched_barrier(0); }
#define WAIT12 asm volatile("s_waitcnt vmcnt(12)" ::: "memory");
#define WAIT6 asm volatile("s_waitcnt vmcnt(6)" ::: "memory");
#define WAIT0 asm volatile("s_waitcnt vmcnt(0)" ::: "memory");

// ======= k_gemm_sm: 128(M)x64(N) tile, 4 waves (2Mx2N), QUAD-buffer 48KB =======
// One barrier per K-tile (vs 2 in dbuf): STAGE(t+2) -> vmcnt(12) -> barrier ->
// COMPUTE(t). RAW: wait drains tile t's 6 loads (oldest of 18), barrier makes
// it collective. WAR: buf[(t+2)&3] last read in COMPUTE(t-2), finished by all
// waves before tile t-1's barrier, which the staging wave passed. Depth-2
// prefetch (~2x flight time). K/N compile-time.
// EPI 1: outB bf16 = resF(f32) + acc + bias        (Wo: y bf16)
// EPI 2: outB bf16 = gelu(acc + bias)              (FFN1 -> U)
// EPI 3: QKV segmented out_bf16[seg][row][col&511]
// EPI 5: outF f32  = resB(bf16) + acc + bias       (FFN2 final)
template <int EPI, int KD, int ND>
__global__ __launch_bounds__(256, 2) void k_gemm_sm(
    const u16* __restrict__ A, const u16* __restrict__ Bt,
    const float* __restrict__ bias, const float* __restrict__ resF,
    const u16* __restrict__ resB, float* __restrict__ outF,
    u16* __restrict__ outB) {
  __shared__ u16 lds[49152];  // buf c at c*12288: A [128][64] @0, B [64][64] @8192
  constexpr int tiles_n = ND / 64;
  const int t = threadIdx.x, wid = t >> 6, lane = t & 63;
  const int nwg = gridDim.x, bid = blockIdx.x;
  const int l = ((bid & 7) * (nwg >> 3)) + (bid >> 3);   // nwg % 8 == 0
  const int bM = (l / tiles_n) * 128, bN = (l % tiles_n) * 64;
  const int wr = wid >> 1, wc = wid & 1, lr = lane & 15, lg = lane >> 4;

  const int rs = lane >> 3;
  const int cl = (lane & 7) ^ rs;        // inverse-swizzled source chunk
  const u16* gA = A + (size_t)(bM + wid * 32 + rs) * KD + cl * 8;   // + j*8*KD
  const u16* gB = Bt + (size_t)(bN + wid * 16 + rs) * KD + cl * 8;  // + j*8*KD
  const int dA = wid * 2048;             // + j*512
  const int dB = 8192 + wid * 1024;      // + j*512

#define STAGE_SM(BUF, KOFF)                                                           \
  {                                                                                   \
    _Pragma("unroll") for (int j = 0; j < 4; ++j)                                     \
      __builtin_amdgcn_global_load_lds(                                               \
          (const __attribute__((address_space(1))) void*)(gA + (size_t)(j * 8 * KD) + (KOFF)), \
          (__attribute__((address_space(3))) void*)(lds + (BUF)*12288 + dA + j * 512),\
          16, 0, 0);                                                                  \
    _Pragma("unroll") for (int j = 0; j < 2; ++j)                                     \
      __builtin_amdgcn_global_load_lds(                                               \
          (const __attribute__((address_space(1))) void*)(gB + (size_t)(j * 8 * KD) + (KOFF)), \
          (__attribute__((address_space(3))) void*)(lds + (BUF)*12288 + dB + j * 512),\
          16, 0, 0);                                                                  \
  }

  const int swz0 = ((0 + lg) ^ (lr & 7)) * 8;
  const int swz1 = ((4 + lg) ^ (lr & 7)) * 8;
  const int offA = (wr * 64 + lr) * 64;          // + mt*1024 + swz
  const int offB = 8192 + (wc * 32 + lr) * 64;   // + nt*1024 + swz

  f32x4 acc[4][2];
#pragma unroll
  for (int i = 0; i < 4; ++i)
#pragma unroll
    for (int j = 0; j < 2; ++j) acc[i][j] = (f32x4){0.f, 0.f, 0.f, 0.f};

#define COMPUTE_SM(BUF)                                                               \
  {                                                                                   \
    _Pragma("unroll") for (int ks = 0; ks < 2; ++ks) {                                \
      const int swz = ks ? swz1 : swz0;                                               \
      bf16x8 af[4], bfr[2];                                                           \
      _Pragma("unroll") for (int mt = 0; mt < 4; ++mt)                                \
          af[mt] = __builtin_bit_cast(bf16x8,                                         \
              *(const uint4*)(lds + (BUF)*12288 + offA + mt * 1024 + swz));           \
      _Pragma("unroll") for (int nt = 0; nt < 2; ++nt)                                \
          bfr[nt] = __builtin_bit_cast(bf16x8,                                        \
              *(const uint4*)(lds + (BUF)*12288 + offB + nt * 1024 + swz));           \
      _Pragma("unroll") for (int mt = 0; mt < 4; ++mt)                                \
          _Pragma("unroll") for (int nt = 0; nt < 2; ++nt)                            \
              acc[mt][nt] = __builtin_amdgcn_mfma_f32_16x16x32_bf16(                  \
                  af[mt], bfr[nt], acc[mt][nt], 0, 0, 0);                             \
    }                                                                                 \
  }

  constexpr int nk = KD >> 6;  // 8 or 32
  // prologue: tiles 0 and 1 into bufs 0,1
  STAGE_SM(0, 0);
  STAGE_SM(1, 64);
#pragma unroll(KD == 512 ? 8 : 1)
  for (int tt = 0; tt < nk; ++tt) {
    const int cb = (tt & 3);
    if (tt + 2 < nk) {
      STAGE_SM((tt + 2) & 3, (tt + 2) << 6);
      WAIT12
    } else if (tt + 1 < nk) {
      WAIT6
    } else {
      WAIT0
    }
    BARR;
    COMPUTE_SM(cb);
  }
#undef STAGE_SM
#undef COMPUTE_SM

  // epilogue: D row = lg*4 + r, col = lr
#pragma unroll
  for (int mt = 0; mt < 4; ++mt) {
#pragma unroll
    for (int nt = 0; nt < 2; ++nt) {
      int col = bN + wc * 32 + nt * 16 + lr;
      float bc = bias[col];
      int row0 = bM + wr * 64 + mt * 16 + lg * 4;
#pragma unroll
      for (int r = 0; r < 4; ++r) {
        float val = acc[mt][nt][r] + bc;
        if constexpr (EPI == 1) {
          size_t off = (size_t)(row0 + r) * ND + col;
          outB[off] = f2bf(resF[off] + val);          // y bf16
        } else if constexpr (EPI == 2) {
          outB[(size_t)(row0 + r) * ND + col] = f2bf(gelu_fast(val));
        } else if constexpr (EPI == 3) {
          int seg = col >> 9;
          size_t off = (size_t)seg * ((size_t)NTOK * DMODEL) +
                       (size_t)(row0 + r) * DMODEL + (col & 511);
          outB[off] = f2bf(val);
        } else {  // EPI == 5
          size_t off = (size_t)(row0 + r) * ND + col;
          outF[off] = bf2f(resB[off]) + val;          // final f32
        }
      }
    }
  }
}

// ---------------- workspace layout ----------------
extern "C" void kernel_launch(void* const* d_in, const int* in_sizes, int n_in,
                              void* d_out, int out_size, void* d_ws, size_t ws_size,
                              hipStream_t stream) {
  const float* x = (const float*)d_in[0];
  const int* gpos = (const int*)d_in[1];
  const float* Wq = (const float*)d_in[2];
  const float* bq = (const float*)d_in[3];
  const float* Wk = (const float*)d_in[4];
  const float* bk = (const float*)d_in[5];
  const float* Wv = (const float*)d_in[6];
  const float* bv = (const float*)d_in[7];
  const float* Wo = (const float*)d_in[8];
  const float* bo = (const float*)d_in[9];
  const float* g1 = (const float*)d_in[10];
  const float* b1 = (const float*)d_in[11];
  const float* g2 = (const float*)d_in[12];
  const float* b2 = (const float*)d_in[13];
  const float* W1 = (const float*)d_in[14];
  const float* bf1 = (const float*)d_in[15];
  const float* W2 = (const float*)d_in[16];
  const float* bf2 = (const float*)d_in[17];
  float* out = (float*)d_out;
  char* ws = (char*)d_ws;

  constexpr size_t SZ_W512 = (size_t)512 * 512 * 2;
  constexpr size_t SZ_W2048 = (size_t)512 * 2048 * 2;
  constexpr size_t SZ_ACT = (size_t)NTOK * 512 * 2;

  u16* WQT = (u16*)(ws + 0);                 // [1536][512] contiguous (Q,K,V)
  u16* WKT = (u16*)(ws + SZ_W512);
  u16* WVT = (u16*)(ws + 2 * SZ_W512);
  u16* WOT = (u16*)(ws + 3 * SZ_W512);
  u16* W1T = (u16*)(ws + 4 * SZ_W512);
  u16* W2T = (u16*)(ws + 4 * SZ_W512 + SZ_W2048);
  float* BCAT = (float*)(ws + 4 * SZ_W512 + 2 * SZ_W2048);  // 1536 f32
  char* actbase = ws + 4 * SZ_W512 + 2 * SZ_W2048 + 6144;
  u16* H = (u16*)(actbase);
  u16* Q = (u16*)(actbase + SZ_ACT);         // Q,K,V contiguous
  u16* KB = (u16*)(actbase + 2 * SZ_ACT);
  u16* VB = (u16*)(actbase + 3 * SZ_ACT);
  u16* H2 = (u16*)(actbase + 4 * SZ_ACT);
  u16* YB = (u16*)(actbase + 5 * SZ_ACT);    // bf16 residual stream y
  u16* U = (u16*)(actbase);                  // [NTOK][2048] overlaps H,Q,K,V

  // merged prep: transposes + bias concat + LN1 (1 launch)
  k_prep<<<5382, 256, 0, stream>>>(Wq, Wk, Wv, Wo, W1, W2, bq, bk, bv, x, g1, b1,
                                   WQT, WKT, WVT, WOT, W1T, W2T, BCAT, H);

  // fused QKV: [NTOK,1536] = H @ [Wq|Wk|Wv]^T  (128x64 tiles: grid 1728)
  k_gemm_sm<3, 512, 1536><<<1728, 256, 0, stream>>>(H, WQT, BCAT, nullptr, nullptr,
                                                    nullptr, Q);

  // local attention -> H (reuse)  [XCD-banded]
  k_attn<<<NTOK / 4, 256, 0, stream>>>(Q, KB, VB, gpos, H);

  // y = bf16(x + attn @ Wo + bo)  (128x64 tiles: grid 576)
  k_gemm_sm<1, 512, 512><<<576, 256, 0, stream>>>(H, WOT, bo, x, nullptr,
                                                  nullptr, YB);

  // LN2: y(bf16) -> h2(bf16)
  k_layernorm_b2b<<<NTOK / 4, 256, 0, stream>>>(YB, g2, b2, H2);

  // u = gelu(h2 @ W1 + bf1)  (128x64 tiles: grid 2304)
  k_gemm_sm<2, 512, 2048><<<2304, 256, 0, stream>>>(H2, W1T, bf1, nullptr, nullptr,
                                                    nullptr, U);

  // out = y(bf16) + u @ W2 + bf2  (128x64 tiles: grid 576)
  k_gemm_sm<5, 2048, 512><<<576, 256, 0, stream>>>(U, W2T, bf2, nullptr, YB,
                                                   out, nullptr);
}

// Round 19
// 139.412 us; speedup vs baseline: 1.2118x; 1.2118x over previous
//
#include <hip/hip_runtime.h>

typedef unsigned short u16;
typedef unsigned int u32;
typedef __bf16 bf16x8 __attribute__((ext_vector_type(8)));
typedef float f32x4 __attribute__((ext_vector_type(4)));

#define GRID_G 96
#define DMODEL 512
#define NTOK (GRID_G * GRID_G)

__device__ __forceinline__ u16 f2bf(float f) {
  return __builtin_bit_cast(u16, (__bf16)f);   // single v_cvt (RNE)
}
__device__ __forceinline__ float bf2f(u16 h) {
  return __builtin_bit_cast(float, ((u32)h) << 16);
}
__device__ __forceinline__ void unpack8(uint4 u, float* f) {
  f[0] = __builtin_bit_cast(float, u.x << 16);
  f[1] = __builtin_bit_cast(float, u.x & 0xffff0000u);
  f[2] = __builtin_bit_cast(float, u.y << 16);
  f[3] = __builtin_bit_cast(float, u.y & 0xffff0000u);
  f[4] = __builtin_bit_cast(float, u.z << 16);
  f[5] = __builtin_bit_cast(float, u.z & 0xffff0000u);
  f[6] = __builtin_bit_cast(float, u.w << 16);
  f[7] = __builtin_bit_cast(float, u.w & 0xffff0000u);
}
// gelu (tanh form, stable): max dev vs erf-gelu ~3e-4 — far under threshold
__device__ __forceinline__ float gelu_fast(float x) {
  float y = 0.7978845608f * (x + 0.044715f * x * x * x);
  float a = fabsf(y);
  float e = __expf(-2.0f * a);
  float th = (1.0f - e) / (1.0f + e);
  th = __builtin_copysignf(th, y);
  return 0.5f * x * (1.0f + th);
}

// ============ merged prep: weight transposes + bias concat + LN1 (1 launch) ============
__device__ __forceinline__ void tr_tile(const float* __restrict__ src,
                                        u16* __restrict__ dst, int R, int C,
                                        int bx, int by, float (*tile)[33]) {
  int tx = threadIdx.x & 31, ty = threadIdx.x >> 5;
#pragma unroll
  for (int i = 0; i < 4; ++i) {
    int r = ty + i * 8;
    tile[r][tx] = src[(size_t)(by * 32 + r) * C + (bx * 32 + tx)];
  }
  __syncthreads();
#pragma unroll
  for (int i = 0; i < 4; ++i) {
    int c = ty + i * 8;
    dst[(size_t)(bx * 32 + c) * R + (by * 32 + tx)] = f2bf(tile[tx][c]);
  }
}

__global__ __launch_bounds__(256) void k_prep(
    const float* __restrict__ Wq, const float* __restrict__ Wk,
    const float* __restrict__ Wv, const float* __restrict__ Wo,
    const float* __restrict__ W1, const float* __restrict__ W2,
    const float* __restrict__ bq, const float* __restrict__ bk,
    const float* __restrict__ bv, const float* __restrict__ x,
    const float* __restrict__ g1, const float* __restrict__ b1,
    u16* __restrict__ WQT, u16* __restrict__ WKT, u16* __restrict__ WVT,
    u16* __restrict__ WOT, u16* __restrict__ W1T, u16* __restrict__ W2T,
    float* __restrict__ BCAT, u16* __restrict__ H) {
  __shared__ float tile[32][33];
  const int b = blockIdx.x;
  if (b < 1024) {            // 4x 512x512 transpose
    int z = b >> 8, sub = b & 255;
    const float* s = z == 0 ? Wq : z == 1 ? Wk : z == 2 ? Wv : Wo;
    u16* d = z == 0 ? WQT : z == 1 ? WKT : z == 2 ? WVT : WOT;
    tr_tile(s, d, 512, 512, sub & 15, sub >> 4, tile);
  } else if (b < 2048) {     // W1 [512][2048] -> W1T [2048][512]
    int idx = b - 1024;
    tr_tile(W1, W1T, 512, 2048, idx & 63, idx >> 6, tile);
  } else if (b < 3072) {     // W2 [2048][512] -> W2T [512][2048]
    int idx = b - 2048;
    tr_tile(W2, W2T, 2048, 512, idx & 15, idx >> 4, tile);
  } else if (b < 3078) {     // bias concat
    int i = (b - 3072) * 256 + threadIdx.x;
    if (i < 512) BCAT[i] = bq[i];
    else if (i < 1024) BCAT[i] = bk[i - 512];
    else if (i < 1536) BCAT[i] = bv[i - 1024];
  } else {                   // LN1: x -> H (bf16), one wave/row
    int tid = threadIdx.x, wid = tid >> 6, lane = tid & 63;
    int row = (b - 3078) * 4 + wid;
    const float* xr = x + (size_t)row * DMODEL;
    float4 v0 = *(const float4*)(xr + lane * 4);
    float4 v1 = *(const float4*)(xr + 256 + lane * 4);
    float s = v0.x + v0.y + v0.z + v0.w + v1.x + v1.y + v1.z + v1.w;
    float sq = v0.x * v0.x + v0.y * v0.y + v0.z * v0.z + v0.w * v0.w +
               v1.x * v1.x + v1.y * v1.y + v1.z * v1.z + v1.w * v1.w;
#pragma unroll
    for (int m = 1; m < 64; m <<= 1) {
      s += __shfl_xor(s, m);
      sq += __shfl_xor(sq, m);
    }
    float mean = s * (1.0f / DMODEL);
    float rstd = rsqrtf(sq * (1.0f / DMODEL) - mean * mean + 1e-5f);
    float4 ga = *(const float4*)(g1 + lane * 4);
    float4 gb = *(const float4*)(g1 + 256 + lane * 4);
    float4 ba = *(const float4*)(b1 + lane * 4);
    float4 bb = *(const float4*)(b1 + 256 + lane * 4);
    ushort4 o0, o1;
    o0.x = f2bf((v0.x - mean) * rstd * ga.x + ba.x);
    o0.y = f2bf((v0.y - mean) * rstd * ga.y + ba.y);
    o0.z = f2bf((v0.z - mean) * rstd * ga.z + ba.z);
    o0.w = f2bf((v0.w - mean) * rstd * ga.w + ba.w);
    o1.x = f2bf((v1.x - mean) * rstd * gb.x + bb.x);
    o1.y = f2bf((v1.y - mean) * rstd * gb.y + bb.y);
    o1.z = f2bf((v1.z - mean) * rstd * gb.z + bb.z);
    o1.w = f2bf((v1.w - mean) * rstd * gb.w + bb.w);
    u16* op = H + (size_t)row * DMODEL;
    *(ushort4*)(op + lane * 4) = o0;
    *(ushort4*)(op + 256 + lane * 4) = o1;
  }
}

// -------- LN2: bf16 y -> bf16 h2, one wave per row --------
__global__ __launch_bounds__(256) void k_layernorm_b2b(
    const u16* __restrict__ yb, const float* __restrict__ g,
    const float* __restrict__ b, u16* __restrict__ out) {
  int tid = threadIdx.x, wid = tid >> 6, lane = tid & 63;
  int row = blockIdx.x * 4 + wid;
  float v[8];
  unpack8(*(const uint4*)(yb + (size_t)row * DMODEL + lane * 8), v);
  float s = 0.f, sq = 0.f;
#pragma unroll
  for (int e = 0; e < 8; ++e) { s += v[e]; sq += v[e] * v[e]; }
#pragma unroll
  for (int m = 1; m < 64; m <<= 1) {
    s += __shfl_xor(s, m);
    sq += __shfl_xor(sq, m);
  }
  float mean = s * (1.0f / DMODEL);
  float rstd = rsqrtf(sq * (1.0f / DMODEL) - mean * mean + 1e-5f);
  float4 ga = *(const float4*)(g + lane * 8);
  float4 gb = *(const float4*)(g + lane * 8 + 4);
  float4 ba = *(const float4*)(b + lane * 8);
  float4 bb = *(const float4*)(b + lane * 8 + 4);
  float gg[8] = {ga.x, ga.y, ga.z, ga.w, gb.x, gb.y, gb.z, gb.w};
  float bbv[8] = {ba.x, ba.y, ba.z, ba.w, bb.x, bb.y, bb.z, bb.w};
  uint4 o;
  u32 r[8];
#pragma unroll
  for (int e = 0; e < 8; ++e) r[e] = f2bf((v[e] - mean) * rstd * gg[e] + bbv[e]);
  o.x = r[0] | (r[1] << 16);
  o.y = r[2] | (r[3] << 16);
  o.z = r[4] | (r[5] << 16);
  o.w = r[6] | (r[7] << 16);
  *(uint4*)(out + (size_t)row * DMODEL + lane * 8) = o;
}

// ---------- local attention: one wave/token, 4x16-lane group reduction ----------
__global__ __launch_bounds__(256) void k_attn(
    const u16* __restrict__ q, const u16* __restrict__ kk,
    const u16* __restrict__ vv, const int* __restrict__ gpos,
    u16* __restrict__ out) {
  int tid = threadIdx.x, wid = tid >> 6, lane = tid & 63;
  const int nwg = gridDim.x, bid = blockIdx.x;
  const int l = ((bid & 7) * (nwg >> 3)) + (bid >> 3);   // nwg % 8 == 0
  int n = l * 4 + wid;
  int px = gpos[2 * n], py = gpos[2 * n + 1];
  const int g = lane >> 4, li = lane & 15;

  float qf[4][8];
#pragma unroll
  for (int i = 0; i < 4; ++i)
    unpack8(*(const uint4*)(q + (size_t)n * DMODEL + (li + 16 * i) * 8), qf[i]);

  float myw[6];
  bool myok[6];
#pragma unroll
  for (int jr = 0; jr < 6; ++jr) {
    int j = jr * 4 + g;
    int jj = j < 12 ? j : j + 1;           // skip (0,0)
    int dx = jj / 5 - 2, dy = jj % 5 - 2;
    int nx = px + dx, ny = py + dy;
    bool ok = (nx >= 0) && (nx < GRID_G) && (ny >= 0) && (ny < GRID_G);
    int id = ok ? nx * GRID_G + ny : 0;
    myok[jr] = ok;
    const u16* kr = kk + (size_t)id * DMODEL;
    float p = 0.f;
#pragma unroll
    for (int i = 0; i < 4; ++i) {
      float kf[8];
      unpack8(*(const uint4*)(kr + (li + 16 * i) * 8), kf);
#pragma unroll
      for (int e = 0; e < 8; ++e) p += qf[i][e] * kf[e];
    }
    p += __shfl_xor(p, 1);
    p += __shfl_xor(p, 2);
    p += __shfl_xor(p, 4);
    p += __shfl_xor(p, 8);
    myw[jr] = p * 0.04419417382415922f;    // 1/sqrt(512)
  }
  float mx = -3.0e38f;
#pragma unroll
  for (int jr = 0; jr < 6; ++jr)
    if (myok[jr]) mx = fmaxf(mx, myw[jr]);
  mx = fmaxf(mx, __shfl_xor(mx, 16));
  mx = fmaxf(mx, __shfl_xor(mx, 32));
  float ws = 0.f;
#pragma unroll
  for (int jr = 0; jr < 6; ++jr) {
    myw[jr] = myok[jr] ? __expf(myw[jr] - mx) : 0.f;
    ws += myw[jr];
  }
  ws += __shfl_xor(ws, 16);
  ws += __shfl_xor(ws, 32);
  float inv = __builtin_amdgcn_rcpf(ws);   // err ~1e-6, negligible

  float acc[8] = {0, 0, 0, 0, 0, 0, 0, 0};
#pragma unroll
  for (int j = 0; j < 24; ++j) {
    float wj = __shfl(myw[j >> 2], (j & 3) * 16);   // group (j&3) holds it
    int jj = j < 12 ? j : j + 1;
    int dx = jj / 5 - 2, dy = jj % 5 - 2;
    int nx = px + dx, ny = py + dy;
    bool ok = (nx >= 0) && (nx < GRID_G) && (ny >= 0) && (ny < GRID_G);
    int id = ok ? nx * GRID_G + ny : 0;    // wj==0 for invalid -> harmless
    float vf[8];
    unpack8(*(const uint4*)(vv + (size_t)id * DMODEL + lane * 8), vf);
#pragma unroll
    for (int e = 0; e < 8; ++e) acc[e] += wj * vf[e];
  }
  uint4 o;
  o.x = (u32)f2bf(acc[0] * inv) | ((u32)f2bf(acc[1] * inv) << 16);
  o.y = (u32)f2bf(acc[2] * inv) | ((u32)f2bf(acc[3] * inv) << 16);
  o.z = (u32)f2bf(acc[4] * inv) | ((u32)f2bf(acc[5] * inv) << 16);
  o.w = (u32)f2bf(acc[6] * inv) | ((u32)f2bf(acc[7] * inv) << 16);
  *(uint4*)(out + (size_t)n * DMODEL + lane * 8) = o;
}

#define BARR { __builtin_amdgcn_s_barrier(); __builtin_amdgcn_sched_barrier(0); }
#define WAIT6 asm volatile("s_waitcnt vmcnt(6)" ::: "memory");
#define WAIT0 asm volatile("s_waitcnt vmcnt(0)" ::: "memory");

// ======= k_gemm_sm: 128(M)x64(N) tile, 4 waves (2Mx2N), dbuf 48KB, vmcnt(6) =======
// K/N COMPILE-TIME (template): stage offsets j*8*K and epilogue row*N fold
// into immediates; K=512's 8-tile loop fully unrolls. (r17-proven, 139.6us)
// EPI 1: outB bf16 = resF(f32) + acc + bias        (Wo: y bf16)
// EPI 2: outB bf16 = gelu(acc + bias)              (FFN1 -> U)
// EPI 3: QKV segmented out_bf16[seg][row][col&511]
// EPI 5: outF f32  = resB(bf16) + acc + bias       (FFN2 final)
template <int EPI, int KD, int ND>
__global__ __launch_bounds__(256, 2) void k_gemm_sm(
    const u16* __restrict__ A, const u16* __restrict__ Bt,
    const float* __restrict__ bias, const float* __restrict__ resF,
    const u16* __restrict__ resB, float* __restrict__ outF,
    u16* __restrict__ outB) {
  __shared__ u16 lds[24576];  // buf c at c*12288: A [128][64] @0, B [64][64] @8192
  constexpr int tiles_n = ND / 64;
  const int t = threadIdx.x, wid = t >> 6, lane = t & 63;
  const int nwg = gridDim.x, bid = blockIdx.x;
  const int l = ((bid & 7) * (nwg >> 3)) + (bid >> 3);   // nwg % 8 == 0
  const int bM = (l / tiles_n) * 128, bN = (l % tiles_n) * 64;
  const int wr = wid >> 1, wc = wid & 1, lr = lane & 15, lg = lane >> 4;

  const int rs = lane >> 3;
  const int cl = (lane & 7) ^ rs;        // inverse-swizzled source chunk
  const u16* gA = A + (size_t)(bM + wid * 32 + rs) * KD + cl * 8;   // + j*8*KD
  const u16* gB = Bt + (size_t)(bN + wid * 16 + rs) * KD + cl * 8;  // + j*8*KD
  const int dA = wid * 2048;             // + j*512
  const int dB = 8192 + wid * 1024;      // + j*512

#define STAGE_SM(BUF, KOFF)                                                           \
  {                                                                                   \
    _Pragma("unroll") for (int j = 0; j < 4; ++j)                                     \
      __builtin_amdgcn_global_load_lds(                                               \
          (const __attribute__((address_space(1))) void*)(gA + (size_t)(j * 8 * KD) + (KOFF)), \
          (__attribute__((address_space(3))) void*)(lds + (BUF)*12288 + dA + j * 512),\
          16, 0, 0);                                                                  \
    _Pragma("unroll") for (int j = 0; j < 2; ++j)                                     \
      __builtin_amdgcn_global_load_lds(                                               \
          (const __attribute__((address_space(1))) void*)(gB + (size_t)(j * 8 * KD) + (KOFF)), \
          (__attribute__((address_space(3))) void*)(lds + (BUF)*12288 + dB + j * 512),\
          16, 0, 0);                                                                  \
  }

  const int swz0 = ((0 + lg) ^ (lr & 7)) * 8;
  const int swz1 = ((4 + lg) ^ (lr & 7)) * 8;
  const int offA = (wr * 64 + lr) * 64;          // + mt*1024 + swz
  const int offB = 8192 + (wc * 32 + lr) * 64;   // + nt*1024 + swz

  f32x4 acc[4][2];
#pragma unroll
  for (int i = 0; i < 4; ++i)
#pragma unroll
    for (int j = 0; j < 2; ++j) acc[i][j] = (f32x4){0.f, 0.f, 0.f, 0.f};

#define COMPUTE_SM(BUF)                                                               \
  {                                                                                   \
    _Pragma("unroll") for (int ks = 0; ks < 2; ++ks) {                                \
      const int swz = ks ? swz1 : swz0;                                               \
      bf16x8 af[4], bfr[2];                                                           \
      _Pragma("unroll") for (int mt = 0; mt < 4; ++mt)                                \
          af[mt] = __builtin_bit_cast(bf16x8,                                         \
              *(const uint4*)(lds + (BUF)*12288 + offA + mt * 1024 + swz));           \
      _Pragma("unroll") for (int nt = 0; nt < 2; ++nt)                                \
          bfr[nt] = __builtin_bit_cast(bf16x8,                                        \
              *(const uint4*)(lds + (BUF)*12288 + offB + nt * 1024 + swz));           \
      _Pragma("unroll") for (int mt = 0; mt < 4; ++mt)                                \
          _Pragma("unroll") for (int nt = 0; nt < 2; ++nt)                            \
              acc[mt][nt] = __builtin_amdgcn_mfma_f32_16x16x32_bf16(                  \
                  af[mt], bfr[nt], acc[mt][nt], 0, 0, 0);                             \
    }                                                                                 \
  }

  constexpr int nk = KD >> 6;  // 8 or 32 (even)
  STAGE_SM(0, 0);
  int koff = 64;
#pragma unroll(KD == 512 ? 4 : 1)
  for (int tt = 0; tt < nk; tt += 2) {
    if (tt + 1 < nk) { STAGE_SM(1, koff); WAIT6 } else { WAIT0 }
    BARR;
    COMPUTE_SM(0);
    BARR;
    if (tt + 2 < nk) { STAGE_SM(0, koff + 64); WAIT6 } else { WAIT0 }
    BARR;
    COMPUTE_SM(1);
    BARR;
    koff += 128;
  }
#undef STAGE_SM
#undef COMPUTE_SM

  // epilogue: D row = lg*4 + r, col = lr
#pragma unroll
  for (int mt = 0; mt < 4; ++mt) {
#pragma unroll
    for (int nt = 0; nt < 2; ++nt) {
      int col = bN + wc * 32 + nt * 16 + lr;
      float bc = bias[col];
      int row0 = bM + wr * 64 + mt * 16 + lg * 4;
#pragma unroll
      for (int r = 0; r < 4; ++r) {
        float val = acc[mt][nt][r] + bc;
        if constexpr (EPI == 1) {
          size_t off = (size_t)(row0 + r) * ND + col;
          outB[off] = f2bf(resF[off] + val);          // y bf16
        } else if constexpr (EPI == 2) {
          outB[(size_t)(row0 + r) * ND + col] = f2bf(gelu_fast(val));
        } else if constexpr (EPI == 3) {
          int seg = col >> 9;
          size_t off = (size_t)seg * ((size_t)NTOK * DMODEL) +
                       (size_t)(row0 + r) * DMODEL + (col & 511);
          outB[off] = f2bf(val);
        } else {  // EPI == 5
          size_t off = (size_t)(row0 + r) * ND + col;
          outF[off] = bf2f(resB[off]) + val;          // final f32
        }
      }
    }
  }
}

// ---------------- workspace layout ----------------
extern "C" void kernel_launch(void* const* d_in, const int* in_sizes, int n_in,
                              void* d_out, int out_size, void* d_ws, size_t ws_size,
                              hipStream_t stream) {
  const float* x = (const float*)d_in[0];
  const int* gpos = (const int*)d_in[1];
  const float* Wq = (const float*)d_in[2];
  const float* bq = (const float*)d_in[3];
  const float* Wk = (const float*)d_in[4];
  const float* bk = (const float*)d_in[5];
  const float* Wv = (const float*)d_in[6];
  const float* bv = (const float*)d_in[7];
  const float* Wo = (const float*)d_in[8];
  const float* bo = (const float*)d_in[9];
  const float* g1 = (const float*)d_in[10];
  const float* b1 = (const float*)d_in[11];
  const float* g2 = (const float*)d_in[12];
  const float* b2 = (const float*)d_in[13];
  const float* W1 = (const float*)d_in[14];
  const float* bf1 = (const float*)d_in[15];
  const float* W2 = (const float*)d_in[16];
  const float* bf2 = (const float*)d_in[17];
  float* out = (float*)d_out;
  char* ws = (char*)d_ws;

  constexpr size_t SZ_W512 = (size_t)512 * 512 * 2;
  constexpr size_t SZ_W2048 = (size_t)512 * 2048 * 2;
  constexpr size_t SZ_ACT = (size_t)NTOK * 512 * 2;

  u16* WQT = (u16*)(ws + 0);                 // [1536][512] contiguous (Q,K,V)
  u16* WKT = (u16*)(ws + SZ_W512);
  u16* WVT = (u16*)(ws + 2 * SZ_W512);
  u16* WOT = (u16*)(ws + 3 * SZ_W512);
  u16* W1T = (u16*)(ws + 4 * SZ_W512);
  u16* W2T = (u16*)(ws + 4 * SZ_W512 + SZ_W2048);
  float* BCAT = (float*)(ws + 4 * SZ_W512 + 2 * SZ_W2048);  // 1536 f32
  char* actbase = ws + 4 * SZ_W512 + 2 * SZ_W2048 + 6144;
  u16* H = (u16*)(actbase);
  u16* Q = (u16*)(actbase + SZ_ACT);         // Q,K,V contiguous
  u16* KB = (u16*)(actbase + 2 * SZ_ACT);
  u16* VB = (u16*)(actbase + 3 * SZ_ACT);
  u16* H2 = (u16*)(actbase + 4 * SZ_ACT);
  u16* YB = (u16*)(actbase + 5 * SZ_ACT);    // bf16 residual stream y
  u16* U = (u16*)(actbase);                  // [NTOK][2048] overlaps H,Q,K,V

  // merged prep: transposes + bias concat + LN1 (1 launch)
  k_prep<<<5382, 256, 0, stream>>>(Wq, Wk, Wv, Wo, W1, W2, bq, bk, bv, x, g1, b1,
                                   WQT, WKT, WVT, WOT, W1T, W2T, BCAT, H);

  // fused QKV: [NTOK,1536] = H @ [Wq|Wk|Wv]^T  (128x64 tiles: grid 1728)
  k_gemm_sm<3, 512, 1536><<<1728, 256, 0, stream>>>(H, WQT, BCAT, nullptr, nullptr,
                                                    nullptr, Q);

  // local attention -> H (reuse)  [XCD-banded]
  k_attn<<<NTOK / 4, 256, 0, stream>>>(Q, KB, VB, gpos, H);

  // y = bf16(x + attn @ Wo + bo)  (128x64 tiles: grid 576)
  k_gemm_sm<1, 512, 512><<<576, 256, 0, stream>>>(H, WOT, bo, x, nullptr,
                                                  nullptr, YB);

  // LN2: y(bf16) -> h2(bf16)
  k_layernorm_b2b<<<NTOK / 4, 256, 0, stream>>>(YB, g2, b2, H2);

  // u = gelu(h2 @ W1 + bf1)  (128x64 tiles: grid 2304)
  k_gemm_sm<2, 512, 2048><<<2304, 256, 0, stream>>>(H2, W1T, bf1, nullptr, nullptr,
                                                    nullptr, U);

  // out = y(bf16) + u @ W2 + bf2  (128x64 tiles: grid 576)
  k_gemm_sm<5, 2048, 512><<<576, 256, 0, stream>>>(U, W2T, bf2, nullptr, YB,
                                                   out, nullptr);
}